// Round 8
// baseline (1013.980 us; speedup 1.0000x reference)
//
#include <hip/hip_runtime.h>
#include <hip/hip_bf16.h>
#include <math.h>

#define BB 8
#define NN 1024
#define KK 40
#define EMBD 1024
#define EPSF 1e-5f
#define ROWS 8

// ---------------- xx[b,m] = sum_c x[b,c,m]^2 ----------------
__global__ __launch_bounds__(256) void xx_kernel(const float* __restrict__ x, int C, int bstride,
                                                 float* __restrict__ xx) {
    int idx = blockIdx.x * 256 + threadIdx.x;
    int b = idx >> 10, m = idx & 1023;
    const float* xb = x + (size_t)b * bstride;
    float s = 0.f;
    for (int c = 0; c < C; ++c) { float v = xb[c * NN + m]; s += v * v; }
    xx[idx] = s;
}

// ---------------- knn: 8 query rows per block, float4 panel loads, register selection ----------------
__global__ __launch_bounds__(256) void knn_kernel(const float* __restrict__ x, int C, int bstride,
                                                  const float* __restrict__ xx, int* __restrict__ gidx) {
    __shared__ float S[ROWS * NN];       // 32 KB
    __shared__ float CENT[64 * ROWS];    // 2 KB
    int tid = threadIdx.x;
    int b = blockIdx.x >> 7;             // NN/ROWS = 128 blocks per batch
    int n0 = (blockIdx.x & 127) * ROWS;
    const float* xb = x + (size_t)b * bstride;

    float acc[ROWS][4];
#pragma unroll
    for (int r = 0; r < ROWS; ++r)
#pragma unroll
        for (int j = 0; j < 4; ++j) acc[r][j] = 0.f;

    for (int c0 = 0; c0 < C; c0 += 64) {
        int cc = C - c0; if (cc > 64) cc = 64;
        for (int t = tid; t < cc * ROWS; t += 256)
            CENT[t] = xb[(c0 + t / ROWS) * NN + n0 + (t & (ROWS - 1))];
        __syncthreads();
        for (int ci = 0; ci < cc; ++ci) {
            float4 xm = *(const float4*)&xb[(c0 + ci) * NN + (tid << 2)];
#pragma unroll
            for (int r = 0; r < ROWS; ++r) {
                float ce = CENT[ci * ROWS + r];
                acc[r][0] = fmaf(ce, xm.x, acc[r][0]);
                acc[r][1] = fmaf(ce, xm.y, acc[r][1]);
                acc[r][2] = fmaf(ce, xm.z, acc[r][2]);
                acc[r][3] = fmaf(ce, xm.w, acc[r][3]);
            }
        }
        __syncthreads();
    }
    {
        float4 xv = *(const float4*)&xx[b * NN + (tid << 2)];
#pragma unroll
        for (int r = 0; r < ROWS; ++r) {
            float4 sv;
            sv.x = 2.f * acc[r][0] - xv.x;
            sv.y = 2.f * acc[r][1] - xv.y;
            sv.z = 2.f * acc[r][2] - xv.z;
            sv.w = 2.f * acc[r][3] - xv.w;
            *(float4*)&S[r * NN + (tid << 2)] = sv;
        }
    }
    __syncthreads();

    // selection: each wave owns 2 rows; 64 lanes x 16 values in registers
    int wave = tid >> 6, lane = tid & 63;
    for (int rr = 0; rr < ROWS / 4; ++rr) {
        int r = wave * (ROWS / 4) + rr;
        float xxn = xx[b * NN + n0 + r];
        float v[16];
#pragma unroll
        for (int j = 0; j < 16; ++j) v[j] = S[r * NN + lane + 64 * j] - xxn;
        int* gi = gidx + ((size_t)b * NN + n0 + r) * KK;
        for (int it = 0; it < KK; ++it) {
            float bv = v[0]; int bj = 0;
#pragma unroll
            for (int j = 1; j < 16; ++j) if (v[j] > bv) { bv = v[j]; bj = j; }
            int bm = lane + 64 * bj;
#pragma unroll
            for (int off = 32; off >= 1; off >>= 1) {
                float ov = __shfl_xor(bv, off);
                int   om = __shfl_xor(bm, off);
                if (ov > bv || (ov == bv && om < bm)) { bv = ov; bm = om; }
            }
            if (lane == 0) gi[it] = bm;
#pragma unroll
            for (int j = 0; j < 16; ++j) if (lane + 64 * j == bm) v[j] = -INFINITY;
        }
    }
}

// ---------------- ya = w_a @ x ; yc = (w_b - w_a) @ x ----------------
__global__ __launch_bounds__(256) void yab_kernel(const float* __restrict__ x, int C, int bstride,
                                                  const float* __restrict__ w, int O,
                                                  float* __restrict__ ya, float* __restrict__ yc) {
    int tid = threadIdx.x;
    int opb = O >> 3;
    int b  = blockIdx.x / opb;
    int o0 = (blockIdx.x % opb) << 3;
    const float* xb = x + (size_t)b * bstride;
    float a[8][4], cv[8][4];
#pragma unroll
    for (int r = 0; r < 8; ++r)
#pragma unroll
        for (int j = 0; j < 4; ++j) { a[r][j] = 0.f; cv[r][j] = 0.f; }
    for (int c = 0; c < C; ++c) {
        float4 xm = *(const float4*)&xb[c * NN + (tid << 2)];
#pragma unroll
        for (int r = 0; r < 8; ++r) {
            const float* wr = w + (size_t)(o0 + r) * 2 * C;
            float wa = wr[c];
            float wc = wr[C + c] - wa;
            a[r][0]  = fmaf(wa, xm.x, a[r][0]);  cv[r][0] = fmaf(wc, xm.x, cv[r][0]);
            a[r][1]  = fmaf(wa, xm.y, a[r][1]);  cv[r][1] = fmaf(wc, xm.y, cv[r][1]);
            a[r][2]  = fmaf(wa, xm.z, a[r][2]);  cv[r][2] = fmaf(wc, xm.z, cv[r][2]);
            a[r][3]  = fmaf(wa, xm.w, a[r][3]);  cv[r][3] = fmaf(wc, xm.w, cv[r][3]);
        }
    }
#pragma unroll
    for (int r = 0; r < 8; ++r) {
        size_t off = ((size_t)b * O + o0 + r) * NN + (tid << 2);
        *(float4*)&ya[off] = *(float4*)&a[r][0];
        *(float4*)&yc[off] = *(float4*)&cv[r][0];
    }
}

// ---------------- gmax: out = lrelu(bn(max_k ya[o][idx]+yc[o][n])), 8 o-rows LDS-staged ----------------
__global__ __launch_bounds__(256) void gmax8_kernel(const float* __restrict__ ya, const float* __restrict__ yc,
                                                    const int* __restrict__ gidx, const float* __restrict__ bnp,
                                                    int O, float* __restrict__ outp, int out_bstride) {
    __shared__ float yrow[8 * NN];       // 32 KB
    int tid = threadIdx.x;
    int nt   = blockIdx.x & 3;
    int rest = blockIdx.x >> 2;
    int opb = O >> 3;
    int oc = rest % opb;
    int b  = rest / opb;
    int o0 = oc << 3;
    int n  = (nt << 8) + tid;

    for (int t = tid; t < 8 * NN; t += 256)
        yrow[t] = ya[((size_t)b * O + o0 + (t >> 10)) * NN + (t & 1023)];
    __syncthreads();

    int idx[KK];
    const int* gi = gidx + ((size_t)b * NN + n) * KK;
#pragma unroll
    for (int k = 0; k < KK; ++k) idx[k] = gi[k];

#pragma unroll
    for (int r = 0; r < 8; ++r) {
        float m = -INFINITY;
#pragma unroll 8
        for (int k = 0; k < KK; ++k) m = fmaxf(m, yrow[r * NN + idx[k]]);
        m += yc[((size_t)b * O + o0 + r) * NN + n];
        int o = o0 + r;
        float sc = bnp[o] * rsqrtf(bnp[3 * O + o] + EPSF);
        float t0 = (m - bnp[2 * O + o]) * sc + bnp[O + o];
        outp[(size_t)b * out_bstride + (size_t)o * NN + n] = t0 >= 0.f ? t0 : 0.2f * t0;
    }
}

// ---------------- emb: 1024 threads, 1 n/thread, 16 o; bn5+lrelu fused with max+mean pool ----------------
__global__ __launch_bounds__(1024) void emb_kernel(const float* __restrict__ xc, const float* __restrict__ w5,
                                                   const float* __restrict__ bnp, float* __restrict__ g) {
    int tid = threadIdx.x;               // n
    int b  = blockIdx.x >> 6;
    int o0 = (blockIdx.x & 63) << 4;
    const float* xcb = xc + (size_t)b * 512 * NN + tid;
    float acc[16];
#pragma unroll
    for (int r = 0; r < 16; ++r) acc[r] = 0.f;
    for (int c = 0; c < 512; ++c) {
        float xv = xcb[c * NN];
#pragma unroll
        for (int r = 0; r < 16; ++r)
            acc[r] = fmaf(w5[(size_t)(o0 + r) * 512 + c], xv, acc[r]);
    }
    int lane = tid & 63, wave = tid >> 6;   // 16 waves
    __shared__ float rmax[16][16], rsum[16][16];
#pragma unroll
    for (int r = 0; r < 16; ++r) {
        int o = o0 + r;
        float sc = bnp[o] * rsqrtf(bnp[3 * EMBD + o] + EPSF);
        float t0 = (acc[r] - bnp[2 * EMBD + o]) * sc + bnp[EMBD + o];
        t0 = t0 >= 0.f ? t0 : 0.2f * t0;
        float vmax = t0, vsum = t0;
#pragma unroll
        for (int off = 32; off >= 1; off >>= 1) {
            vmax = fmaxf(vmax, __shfl_xor(vmax, off));
            vsum += __shfl_xor(vsum, off);
        }
        if (lane == 0) { rmax[r][wave] = vmax; rsum[r][wave] = vsum; }
    }
    __syncthreads();
    if (tid < 16) {
        float vm = -INFINITY, vs = 0.f;
#pragma unroll
        for (int w = 0; w < 16; ++w) { vm = fmaxf(vm, rmax[tid][w]); vs += rsum[tid][w]; }
        g[(size_t)b * 2 * EMBD + o0 + tid] = vm;
        g[(size_t)b * 2 * EMBD + EMBD + o0 + tid] = vs * (1.0f / 1024.0f);
    }
}

// ---------------- naive head1: one block per (b,o) ----------------
__global__ __launch_bounds__(256) void head1_naive_kernel(const float* __restrict__ g, const float* __restrict__ l1,
                                                          const float* __restrict__ bnp, float* __restrict__ h1) {
    __shared__ float red[256];
    int tid = threadIdx.x;
    int b = blockIdx.x >> 9, o = blockIdx.x & 511;
    const float* gr = g + (size_t)b * 2 * EMBD;
    const float* lr = l1 + (size_t)o * 2 * EMBD;
    float s = 0.f;
    for (int c = tid; c < 2048; c += 256) s = fmaf(gr[c], lr[c], s);
    red[tid] = s;
    __syncthreads();
    for (int st = 128; st >= 1; st >>= 1) {
        if (tid < st) red[tid] += red[tid + st];
        __syncthreads();
    }
    if (tid == 0) {
        float sc = bnp[o] * rsqrtf(bnp[3 * 512 + o] + EPSF);
        float t0 = (red[0] - bnp[2 * 512 + o]) * sc + bnp[512 + o];
        h1[b * 512 + o] = t0 >= 0.f ? t0 : 0.2f * t0;
    }
}

// ---------------- naive head2: one block per (b,o) ----------------
__global__ __launch_bounds__(256) void head2_naive_kernel(const float* __restrict__ h1, const float* __restrict__ l2w,
                                                          const float* __restrict__ l2b, const float* __restrict__ bnp,
                                                          float* __restrict__ h2) {
    __shared__ float red[256];
    int tid = threadIdx.x;
    int b = blockIdx.x >> 8, o = blockIdx.x & 255;
    const float* hr = h1 + (size_t)b * 512;
    const float* lr = l2w + (size_t)o * 512;
    float s = fmaf(hr[tid], lr[tid], hr[tid + 256] * lr[tid + 256]);
    red[tid] = s;
    __syncthreads();
    for (int st = 128; st >= 1; st >>= 1) {
        if (tid < st) red[tid] += red[tid + st];
        __syncthreads();
    }
    if (tid == 0) {
        float v = red[0] + l2b[o];
        float sc = bnp[o] * rsqrtf(bnp[3 * 256 + o] + EPSF);
        float t0 = (v - bnp[2 * 256 + o]) * sc + bnp[256 + o];
        h2[b * 256 + o] = t0 >= 0.f ? t0 : 0.2f * t0;
    }
}

// ---------------- naive head3: one block per (b,i) -> logits scratch ----------------
__global__ __launch_bounds__(256) void head3_naive_kernel(const float* __restrict__ h2, const float* __restrict__ l3w,
                                                          const float* __restrict__ l3b, float* __restrict__ logits) {
    __shared__ float red[256];
    int tid = threadIdx.x;
    int b = blockIdx.x / 40, i = blockIdx.x % 40;
    red[tid] = h2[(size_t)b * 256 + tid] * l3w[(size_t)i * 256 + tid];
    __syncthreads();
    for (int st = 128; st >= 1; st >>= 1) {
        if (tid < st) red[tid] += red[tid + st];
        __syncthreads();
    }
    if (tid == 0) logits[b * 40 + i] = red[0] + l3b[i];
}

// ---------------- final: out[0..319]=logits (f32), out[320..639]=log_softmax (f32) ----------------
__global__ void final_kernel(const float* __restrict__ logits, float* __restrict__ outp) {
    int b = blockIdx.x;
    if (threadIdx.x != 0) return;
    const float* lr = logits + b * 40;
    float mx = lr[0];
    for (int i = 1; i < 40; ++i) mx = fmaxf(mx, lr[i]);
    float se = 0.f;
    for (int i = 0; i < 40; ++i) se += expf(lr[i] - mx);
    float lse = logf(se);
    for (int i = 0; i < 40; ++i) {
        outp[b * 40 + i]            = lr[i];
        outp[BB * 40 + b * 40 + i]  = lr[i] - mx - lse;
    }
}

extern "C" void kernel_launch(void* const* d_in, const int* in_sizes, int n_in,
                              void* d_out, int out_size, void* d_ws, size_t ws_size,
                              hipStream_t stream) {
    const float* x   = (const float*)d_in[0];
    const float* w1  = (const float*)d_in[1];
    const float* w2  = (const float*)d_in[2];
    const float* w3  = (const float*)d_in[3];
    const float* w4  = (const float*)d_in[4];
    const float* w5  = (const float*)d_in[5];
    const float* l1  = (const float*)d_in[6];
    const float* l2w = (const float*)d_in[7];
    const float* l2b = (const float*)d_in[8];
    const float* l3w = (const float*)d_in[9];
    const float* l3b = (const float*)d_in[10];
    const float* bn1 = (const float*)d_in[11];
    const float* bn2 = (const float*)d_in[12];
    const float* bn3 = (const float*)d_in[13];
    const float* bn4 = (const float*)d_in[14];
    const float* bn5 = (const float*)d_in[15];
    const float* bn6 = (const float*)d_in[16];
    const float* bn7 = (const float*)d_in[17];
    float* outp = (float*)d_out;   // reference outputs are float32

    // workspace carve (floats): xc | ya | yc | xx | gidx | g | h1 | h2 | logits
    float* xc     = (float*)d_ws;
    float* ya     = xc  + (size_t)BB * 512 * NN;
    float* ycb    = ya  + (size_t)BB * 256 * NN;
    float* xxb    = ycb + (size_t)BB * 256 * NN;
    int*  gidx    = (int*)(xxb + BB * NN);
    float* g      = (float*)(gidx + (size_t)BB * NN * KK);
    float* h1     = g  + BB * 2 * EMBD;
    float* h2     = h1 + BB * 512;
    float* logits = h2 + BB * 256;

    struct Layer { const float* xin; int C; int bstride; const float* w; const float* bn; int O; float* out; };
    Layer L[4] = {
        { x,            3,   3 * NN,   w1, bn1, 64,  xc            },
        { xc,           64,  512 * NN, w2, bn2, 64,  xc + 64 * NN  },
        { xc + 64 * NN, 64,  512 * NN, w3, bn3, 128, xc + 128 * NN },
        { xc + 128 * NN,128, 512 * NN, w4, bn4, 256, xc + 256 * NN },
    };

    for (int i = 0; i < 4; ++i) {
        xx_kernel<<<dim3(BB * NN / 256), dim3(256), 0, stream>>>(L[i].xin, L[i].C, L[i].bstride, xxb);
        knn_kernel<<<dim3(BB * (NN / ROWS)), dim3(256), 0, stream>>>(L[i].xin, L[i].C, L[i].bstride, xxb, gidx);
        yab_kernel<<<dim3(BB * L[i].O / 8), dim3(256), 0, stream>>>(L[i].xin, L[i].C, L[i].bstride, L[i].w, L[i].O, ya, ycb);
        gmax8_kernel<<<dim3(BB * (L[i].O / 8) * 4), dim3(256), 0, stream>>>(ya, ycb, gidx, L[i].bn, L[i].O, L[i].out, 512 * NN);
    }
    emb_kernel<<<dim3(BB * 64), dim3(1024), 0, stream>>>(xc, w5, bn5, g);
    head1_naive_kernel<<<dim3(BB * 512), dim3(256), 0, stream>>>(g, l1, bn6, h1);
    head2_naive_kernel<<<dim3(BB * 256), dim3(256), 0, stream>>>(h1, l2w, l2b, bn7, h2);
    head3_naive_kernel<<<dim3(BB * 40), dim3(256), 0, stream>>>(h2, l3w, l3b, logits);
    final_kernel<<<dim3(BB), dim3(64), 0, stream>>>(logits, outp);
}

// Round 9
// 958.992 us; speedup vs baseline: 1.0573x; 1.0573x over previous
//
#include <hip/hip_runtime.h>
#include <hip/hip_bf16.h>
#include <math.h>

#define BB 8
#define NN 1024
#define KK 40
#define EMBD 1024
#define EPSF 1e-5f
#define ROWS 8
#define BBNN (BB * NN)

// ---------------- xx[b,m] = sum_c x[b,c,m]^2 ----------------
__global__ __launch_bounds__(256) void xx_kernel(const float* __restrict__ x, int C, int bstride,
                                                 float* __restrict__ xx) {
    int idx = blockIdx.x * 256 + threadIdx.x;
    int b = idx >> 10, m = idx & 1023;
    const float* xb = x + (size_t)b * bstride;
    float s = 0.f;
    for (int c = 0; c < C; ++c) { float v = xb[c * NN + m]; s += v * v; }
    xx[idx] = s;
}

// ---------------- knn: 8 query rows per block, float4 panel loads, register selection ----------------
// writes gidx TRANSPOSED: gidx[k * BBNN + b*NN + n]
__global__ __launch_bounds__(256) void knn_kernel(const float* __restrict__ x, int C, int bstride,
                                                  const float* __restrict__ xx, int* __restrict__ gidx) {
    __shared__ float S[ROWS * NN];       // 32 KB
    __shared__ float CENT[64 * ROWS];    // 2 KB
    int tid = threadIdx.x;
    int b = blockIdx.x >> 7;             // NN/ROWS = 128 blocks per batch
    int n0 = (blockIdx.x & 127) * ROWS;
    const float* xb = x + (size_t)b * bstride;

    float acc[ROWS][4];
#pragma unroll
    for (int r = 0; r < ROWS; ++r)
#pragma unroll
        for (int j = 0; j < 4; ++j) acc[r][j] = 0.f;

    for (int c0 = 0; c0 < C; c0 += 64) {
        int cc = C - c0; if (cc > 64) cc = 64;
        for (int t = tid; t < cc * ROWS; t += 256)
            CENT[t] = xb[(c0 + t / ROWS) * NN + n0 + (t & (ROWS - 1))];
        __syncthreads();
        for (int ci = 0; ci < cc; ++ci) {
            float4 xm = *(const float4*)&xb[(c0 + ci) * NN + (tid << 2)];
#pragma unroll
            for (int r = 0; r < ROWS; ++r) {
                float ce = CENT[ci * ROWS + r];
                acc[r][0] = fmaf(ce, xm.x, acc[r][0]);
                acc[r][1] = fmaf(ce, xm.y, acc[r][1]);
                acc[r][2] = fmaf(ce, xm.z, acc[r][2]);
                acc[r][3] = fmaf(ce, xm.w, acc[r][3]);
            }
        }
        __syncthreads();
    }
    {
        float4 xv = *(const float4*)&xx[b * NN + (tid << 2)];
#pragma unroll
        for (int r = 0; r < ROWS; ++r) {
            float4 sv;
            sv.x = 2.f * acc[r][0] - xv.x;
            sv.y = 2.f * acc[r][1] - xv.y;
            sv.z = 2.f * acc[r][2] - xv.z;
            sv.w = 2.f * acc[r][3] - xv.w;
            *(float4*)&S[r * NN + (tid << 2)] = sv;
        }
    }
    __syncthreads();

    // selection: each wave owns 2 rows; 64 lanes x 16 values in registers
    int wave = tid >> 6, lane = tid & 63;
    for (int rr = 0; rr < ROWS / 4; ++rr) {
        int r = wave * (ROWS / 4) + rr;
        float xxn = xx[b * NN + n0 + r];
        float v[16];
#pragma unroll
        for (int j = 0; j < 16; ++j) v[j] = S[r * NN + lane + 64 * j] - xxn;
        int* gi = gidx + (size_t)b * NN + n0 + r;
        for (int it = 0; it < KK; ++it) {
            float bv = v[0]; int bj = 0;
#pragma unroll
            for (int j = 1; j < 16; ++j) if (v[j] > bv) { bv = v[j]; bj = j; }
            int bm = lane + 64 * bj;
#pragma unroll
            for (int off = 32; off >= 1; off >>= 1) {
                float ov = __shfl_xor(bv, off);
                int   om = __shfl_xor(bm, off);
                if (ov > bv || (ov == bv && om < bm)) { bv = ov; bm = om; }
            }
            if (lane == 0) gi[(size_t)it * BBNN] = bm;
#pragma unroll
            for (int j = 0; j < 16; ++j) if (lane + 64 * j == bm) v[j] = -INFINITY;
        }
    }
}

// ---------------- ya = w_a @ x ; yc = (w_b - w_a) @ x ----------------
__global__ __launch_bounds__(256) void yab_kernel(const float* __restrict__ x, int C, int bstride,
                                                  const float* __restrict__ w, int O,
                                                  float* __restrict__ ya, float* __restrict__ yc) {
    int tid = threadIdx.x;
    int opb = O >> 3;
    int b  = blockIdx.x / opb;
    int o0 = (blockIdx.x % opb) << 3;
    const float* xb = x + (size_t)b * bstride;
    float a[8][4], cv[8][4];
#pragma unroll
    for (int r = 0; r < 8; ++r)
#pragma unroll
        for (int j = 0; j < 4; ++j) { a[r][j] = 0.f; cv[r][j] = 0.f; }
    for (int c = 0; c < C; ++c) {
        float4 xm = *(const float4*)&xb[c * NN + (tid << 2)];
#pragma unroll
        for (int r = 0; r < 8; ++r) {
            const float* wr = w + (size_t)(o0 + r) * 2 * C;
            float wa = wr[c];
            float wc = wr[C + c] - wa;
            a[r][0]  = fmaf(wa, xm.x, a[r][0]);  cv[r][0] = fmaf(wc, xm.x, cv[r][0]);
            a[r][1]  = fmaf(wa, xm.y, a[r][1]);  cv[r][1] = fmaf(wc, xm.y, cv[r][1]);
            a[r][2]  = fmaf(wa, xm.z, a[r][2]);  cv[r][2] = fmaf(wc, xm.z, cv[r][2]);
            a[r][3]  = fmaf(wa, xm.w, a[r][3]);  cv[r][3] = fmaf(wc, xm.w, cv[r][3]);
        }
    }
#pragma unroll
    for (int r = 0; r < 8; ++r) {
        size_t off = ((size_t)b * O + o0 + r) * NN + (tid << 2);
        *(float4*)&ya[off] = *(float4*)&a[r][0];
        *(float4*)&yc[off] = *(float4*)&cv[r][0];
    }
}

// ---------------- gmax: out = lrelu(bn(max_k ya[o][idx]+yc[o][n])), 8 o-rows LDS-staged ----------------
// reads gidx TRANSPOSED (coalesced)
__global__ __launch_bounds__(256) void gmax8_kernel(const float* __restrict__ ya, const float* __restrict__ yc,
                                                    const int* __restrict__ gidx, const float* __restrict__ bnp,
                                                    int O, float* __restrict__ outp, int out_bstride) {
    __shared__ float yrow[8 * NN];       // 32 KB
    int tid = threadIdx.x;
    int nt   = blockIdx.x & 3;
    int rest = blockIdx.x >> 2;
    int opb = O >> 3;
    int oc = rest % opb;
    int b  = rest / opb;
    int o0 = oc << 3;
    int n  = (nt << 8) + tid;

    for (int t = tid; t < 8 * NN; t += 256)
        yrow[t] = ya[((size_t)b * O + o0 + (t >> 10)) * NN + (t & 1023)];
    __syncthreads();

    int idx[KK];
    const int* gi = gidx + (size_t)b * NN + n;
#pragma unroll
    for (int k = 0; k < KK; ++k) idx[k] = gi[(size_t)k * BBNN];

#pragma unroll
    for (int r = 0; r < 8; ++r) {
        float m = -INFINITY;
#pragma unroll 8
        for (int k = 0; k < KK; ++k) m = fmaxf(m, yrow[r * NN + idx[k]]);
        m += yc[((size_t)b * O + o0 + r) * NN + n];
        int o = o0 + r;
        float sc = bnp[o] * rsqrtf(bnp[3 * O + o] + EPSF);
        float t0 = (m - bnp[2 * O + o]) * sc + bnp[O + o];
        outp[(size_t)b * out_bstride + (size_t)o * NN + n] = t0 >= 0.f ? t0 : 0.2f * t0;
    }
}

// ---------------- emb v3: XCD-local batches, LDS w5 tile, 8o x 4n per thread ----------------
__global__ __launch_bounds__(256) void emb_kernel(const float* __restrict__ xc, const float* __restrict__ w5,
                                                  const float* __restrict__ bnp, float* __restrict__ g) {
    __shared__ float wlds[8][512];       // 16 KB
    __shared__ float rmax[8][4], rsum[8][4];
    int tid = threadIdx.x;
    int b  = blockIdx.x & 7;             // XCD-local: consecutive blocks -> different XCD -> same b per XCD
    int o0 = (blockIdx.x >> 3) << 3;     // 128 o-blocks of 8
    const float* xcb = xc + (size_t)b * 512 * NN;

    // stage w5[o0..o0+7][0..511] in LDS via float4
#pragma unroll
    for (int i = 0; i < 4; ++i) {
        int t = tid + (i << 8);          // 0..1023 float4 slots
        int row = t >> 7, col = (t & 127) << 2;
        *(float4*)&wlds[row][col] = *(const float4*)&w5[(size_t)(o0 + row) * 512 + col];
    }
    __syncthreads();

    int n4 = tid << 2;
    float acc[8][4];
#pragma unroll
    for (int r = 0; r < 8; ++r)
#pragma unroll
        for (int j = 0; j < 4; ++j) acc[r][j] = 0.f;

    for (int c4 = 0; c4 < 128; ++c4) {
        int c = c4 << 2;
        float4 xm0 = *(const float4*)&xcb[(c + 0) * NN + n4];
        float4 xm1 = *(const float4*)&xcb[(c + 1) * NN + n4];
        float4 xm2 = *(const float4*)&xcb[(c + 2) * NN + n4];
        float4 xm3 = *(const float4*)&xcb[(c + 3) * NN + n4];
#pragma unroll
        for (int r = 0; r < 8; ++r) {
            float4 wv = *(const float4*)&wlds[r][c];
            acc[r][0] = fmaf(wv.x, xm0.x, acc[r][0]);
            acc[r][1] = fmaf(wv.x, xm0.y, acc[r][1]);
            acc[r][2] = fmaf(wv.x, xm0.z, acc[r][2]);
            acc[r][3] = fmaf(wv.x, xm0.w, acc[r][3]);
            acc[r][0] = fmaf(wv.y, xm1.x, acc[r][0]);
            acc[r][1] = fmaf(wv.y, xm1.y, acc[r][1]);
            acc[r][2] = fmaf(wv.y, xm1.z, acc[r][2]);
            acc[r][3] = fmaf(wv.y, xm1.w, acc[r][3]);
            acc[r][0] = fmaf(wv.z, xm2.x, acc[r][0]);
            acc[r][1] = fmaf(wv.z, xm2.y, acc[r][1]);
            acc[r][2] = fmaf(wv.z, xm2.z, acc[r][2]);
            acc[r][3] = fmaf(wv.z, xm2.w, acc[r][3]);
            acc[r][0] = fmaf(wv.w, xm3.x, acc[r][0]);
            acc[r][1] = fmaf(wv.w, xm3.y, acc[r][1]);
            acc[r][2] = fmaf(wv.w, xm3.z, acc[r][2]);
            acc[r][3] = fmaf(wv.w, xm3.w, acc[r][3]);
        }
    }

    int lane = tid & 63, wave = tid >> 6;
#pragma unroll
    for (int r = 0; r < 8; ++r) {
        int o = o0 + r;
        float sc = bnp[o] * rsqrtf(bnp[3 * EMBD + o] + EPSF);
        float mu = bnp[2 * EMBD + o], be = bnp[EMBD + o];
        float vmax = -INFINITY, vsum = 0.f;
#pragma unroll
        for (int j = 0; j < 4; ++j) {
            float t0 = (acc[r][j] - mu) * sc + be;
            t0 = t0 >= 0.f ? t0 : 0.2f * t0;
            vmax = fmaxf(vmax, t0);
            vsum += t0;
        }
#pragma unroll
        for (int off = 32; off >= 1; off >>= 1) {
            vmax = fmaxf(vmax, __shfl_xor(vmax, off));
            vsum += __shfl_xor(vsum, off);
        }
        if (lane == 0) { rmax[r][wave] = vmax; rsum[r][wave] = vsum; }
    }
    __syncthreads();
    if (tid < 8) {
        float vm = fmaxf(fmaxf(rmax[tid][0], rmax[tid][1]), fmaxf(rmax[tid][2], rmax[tid][3]));
        g[(size_t)b * 2 * EMBD + o0 + tid] = vm;
    } else if (tid < 16) {
        int r = tid - 8;
        float vs = rsum[r][0] + rsum[r][1] + rsum[r][2] + rsum[r][3];
        g[(size_t)b * 2 * EMBD + EMBD + o0 + r] = vs * (1.0f / 1024.0f);
    }
}

// ---------------- naive head1: one block per (b,o) ----------------
__global__ __launch_bounds__(256) void head1_naive_kernel(const float* __restrict__ g, const float* __restrict__ l1,
                                                          const float* __restrict__ bnp, float* __restrict__ h1) {
    __shared__ float red[256];
    int tid = threadIdx.x;
    int b = blockIdx.x >> 9, o = blockIdx.x & 511;
    const float* gr = g + (size_t)b * 2 * EMBD;
    const float* lr = l1 + (size_t)o * 2 * EMBD;
    float s = 0.f;
    for (int c = tid; c < 2048; c += 256) s = fmaf(gr[c], lr[c], s);
    red[tid] = s;
    __syncthreads();
    for (int st = 128; st >= 1; st >>= 1) {
        if (tid < st) red[tid] += red[tid + st];
        __syncthreads();
    }
    if (tid == 0) {
        float sc = bnp[o] * rsqrtf(bnp[3 * 512 + o] + EPSF);
        float t0 = (red[0] - bnp[2 * 512 + o]) * sc + bnp[512 + o];
        h1[b * 512 + o] = t0 >= 0.f ? t0 : 0.2f * t0;
    }
}

// ---------------- naive head2: one block per (b,o) ----------------
__global__ __launch_bounds__(256) void head2_naive_kernel(const float* __restrict__ h1, const float* __restrict__ l2w,
                                                          const float* __restrict__ l2b, const float* __restrict__ bnp,
                                                          float* __restrict__ h2) {
    __shared__ float red[256];
    int tid = threadIdx.x;
    int b = blockIdx.x >> 8, o = blockIdx.x & 255;
    const float* hr = h1 + (size_t)b * 512;
    const float* lr = l2w + (size_t)o * 512;
    float s = fmaf(hr[tid], lr[tid], hr[tid + 256] * lr[tid + 256]);
    red[tid] = s;
    __syncthreads();
    for (int st = 128; st >= 1; st >>= 1) {
        if (tid < st) red[tid] += red[tid + st];
        __syncthreads();
    }
    if (tid == 0) {
        float v = red[0] + l2b[o];
        float sc = bnp[o] * rsqrtf(bnp[3 * 256 + o] + EPSF);
        float t0 = (v - bnp[2 * 256 + o]) * sc + bnp[256 + o];
        h2[b * 256 + o] = t0 >= 0.f ? t0 : 0.2f * t0;
    }
}

// ---------------- naive head3: one block per (b,i) -> logits scratch ----------------
__global__ __launch_bounds__(256) void head3_naive_kernel(const float* __restrict__ h2, const float* __restrict__ l3w,
                                                          const float* __restrict__ l3b, float* __restrict__ logits) {
    __shared__ float red[256];
    int tid = threadIdx.x;
    int b = blockIdx.x / 40, i = blockIdx.x % 40;
    red[tid] = h2[(size_t)b * 256 + tid] * l3w[(size_t)i * 256 + tid];
    __syncthreads();
    for (int st = 128; st >= 1; st >>= 1) {
        if (tid < st) red[tid] += red[tid + st];
        __syncthreads();
    }
    if (tid == 0) logits[b * 40 + i] = red[0] + l3b[i];
}

// ---------------- final: out[0..319]=logits (f32), out[320..639]=log_softmax (f32) ----------------
__global__ void final_kernel(const float* __restrict__ logits, float* __restrict__ outp) {
    int b = blockIdx.x;
    if (threadIdx.x != 0) return;
    const float* lr = logits + b * 40;
    float mx = lr[0];
    for (int i = 1; i < 40; ++i) mx = fmaxf(mx, lr[i]);
    float se = 0.f;
    for (int i = 0; i < 40; ++i) se += expf(lr[i] - mx);
    float lse = logf(se);
    for (int i = 0; i < 40; ++i) {
        outp[b * 40 + i]            = lr[i];
        outp[BB * 40 + b * 40 + i]  = lr[i] - mx - lse;
    }
}

extern "C" void kernel_launch(void* const* d_in, const int* in_sizes, int n_in,
                              void* d_out, int out_size, void* d_ws, size_t ws_size,
                              hipStream_t stream) {
    const float* x   = (const float*)d_in[0];
    const float* w1  = (const float*)d_in[1];
    const float* w2  = (const float*)d_in[2];
    const float* w3  = (const float*)d_in[3];
    const float* w4  = (const float*)d_in[4];
    const float* w5  = (const float*)d_in[5];
    const float* l1  = (const float*)d_in[6];
    const float* l2w = (const float*)d_in[7];
    const float* l2b = (const float*)d_in[8];
    const float* l3w = (const float*)d_in[9];
    const float* l3b = (const float*)d_in[10];
    const float* bn1 = (const float*)d_in[11];
    const float* bn2 = (const float*)d_in[12];
    const float* bn3 = (const float*)d_in[13];
    const float* bn4 = (const float*)d_in[14];
    const float* bn5 = (const float*)d_in[15];
    const float* bn6 = (const float*)d_in[16];
    const float* bn7 = (const float*)d_in[17];
    float* outp = (float*)d_out;   // reference outputs are float32

    // workspace carve (floats): xc | ya | yc | xx | gidx | g | h1 | h2 | logits
    float* xc     = (float*)d_ws;
    float* ya     = xc  + (size_t)BB * 512 * NN;
    float* ycb    = ya  + (size_t)BB * 256 * NN;
    float* xxb    = ycb + (size_t)BB * 256 * NN;
    int*  gidx    = (int*)(xxb + BB * NN);
    float* g      = (float*)(gidx + (size_t)BB * NN * KK);
    float* h1     = g  + BB * 2 * EMBD;
    float* h2     = h1 + BB * 512;
    float* logits = h2 + BB * 256;

    struct Layer { const float* xin; int C; int bstride; const float* w; const float* bn; int O; float* out; };
    Layer L[4] = {
        { x,            3,   3 * NN,   w1, bn1, 64,  xc            },
        { xc,           64,  512 * NN, w2, bn2, 64,  xc + 64 * NN  },
        { xc + 64 * NN, 64,  512 * NN, w3, bn3, 128, xc + 128 * NN },
        { xc + 128 * NN,128, 512 * NN, w4, bn4, 256, xc + 256 * NN },
    };

    for (int i = 0; i < 4; ++i) {
        xx_kernel<<<dim3(BB * NN / 256), dim3(256), 0, stream>>>(L[i].xin, L[i].C, L[i].bstride, xxb);
        knn_kernel<<<dim3(BB * (NN / ROWS)), dim3(256), 0, stream>>>(L[i].xin, L[i].C, L[i].bstride, xxb, gidx);
        yab_kernel<<<dim3(BB * L[i].O / 8), dim3(256), 0, stream>>>(L[i].xin, L[i].C, L[i].bstride, L[i].w, L[i].O, ya, ycb);
        gmax8_kernel<<<dim3(BB * (L[i].O / 8) * 4), dim3(256), 0, stream>>>(ya, ycb, gidx, L[i].bn, L[i].O, L[i].out, 512 * NN);
    }
    emb_kernel<<<dim3(BB * 128), dim3(256), 0, stream>>>(xc, w5, bn5, g);
    head1_naive_kernel<<<dim3(BB * 512), dim3(256), 0, stream>>>(g, l1, bn6, h1);
    head2_naive_kernel<<<dim3(BB * 256), dim3(256), 0, stream>>>(h1, l2w, l2b, bn7, h2);
    head3_naive_kernel<<<dim3(BB * 40), dim3(256), 0, stream>>>(h2, l3w, l3b, logits);
    final_kernel<<<dim3(BB), dim3(64), 0, stream>>>(logits, outp);
}

// Round 10
// 905.148 us; speedup vs baseline: 1.1202x; 1.0595x over previous
//
#include <hip/hip_runtime.h>
#include <hip/hip_bf16.h>
#include <math.h>

#define BB 8
#define NN 1024
#define KK 40
#define EMBD 1024
#define EPSF 1e-5f
#define ROWS 8
#define BBNN (BB * NN)

// ---------------- xx[b,m] = sum_c x[b,c,m]^2 ----------------
__global__ __launch_bounds__(256) void xx_kernel(const float* __restrict__ x, int C, int bstride,
                                                 float* __restrict__ xx) {
    int idx = blockIdx.x * 256 + threadIdx.x;
    int b = idx >> 10, m = idx & 1023;
    const float* xb = x + (size_t)b * bstride;
    float s = 0.f;
    for (int c = 0; c < C; ++c) { float v = xb[c * NN + m]; s += v * v; }
    xx[idx] = s;
}

// ---------------- knn: 8 query rows per block, float4 panel loads, register selection ----------------
// writes gidx TRANSPOSED: gidx[k * BBNN + b*NN + n]
__global__ __launch_bounds__(256) void knn_kernel(const float* __restrict__ x, int C, int bstride,
                                                  const float* __restrict__ xx, int* __restrict__ gidx) {
    __shared__ float S[ROWS * NN];       // 32 KB
    __shared__ float CENT[64 * ROWS];    // 2 KB
    int tid = threadIdx.x;
    int b = blockIdx.x >> 7;             // NN/ROWS = 128 blocks per batch
    int n0 = (blockIdx.x & 127) * ROWS;
    const float* xb = x + (size_t)b * bstride;

    float acc[ROWS][4];
#pragma unroll
    for (int r = 0; r < ROWS; ++r)
#pragma unroll
        for (int j = 0; j < 4; ++j) acc[r][j] = 0.f;

    for (int c0 = 0; c0 < C; c0 += 64) {
        int cc = C - c0; if (cc > 64) cc = 64;
        for (int t = tid; t < cc * ROWS; t += 256)
            CENT[t] = xb[(c0 + t / ROWS) * NN + n0 + (t & (ROWS - 1))];
        __syncthreads();
        for (int ci = 0; ci < cc; ++ci) {
            float4 xm = *(const float4*)&xb[(c0 + ci) * NN + (tid << 2)];
#pragma unroll
            for (int r = 0; r < ROWS; ++r) {
                float ce = CENT[ci * ROWS + r];
                acc[r][0] = fmaf(ce, xm.x, acc[r][0]);
                acc[r][1] = fmaf(ce, xm.y, acc[r][1]);
                acc[r][2] = fmaf(ce, xm.z, acc[r][2]);
                acc[r][3] = fmaf(ce, xm.w, acc[r][3]);
            }
        }
        __syncthreads();
    }
    {
        float4 xv = *(const float4*)&xx[b * NN + (tid << 2)];
#pragma unroll
        for (int r = 0; r < ROWS; ++r) {
            float4 sv;
            sv.x = 2.f * acc[r][0] - xv.x;
            sv.y = 2.f * acc[r][1] - xv.y;
            sv.z = 2.f * acc[r][2] - xv.z;
            sv.w = 2.f * acc[r][3] - xv.w;
            *(float4*)&S[r * NN + (tid << 2)] = sv;
        }
    }
    __syncthreads();

    // selection: each wave owns 2 rows; 64 lanes x 16 values in registers
    int wave = tid >> 6, lane = tid & 63;
    for (int rr = 0; rr < ROWS / 4; ++rr) {
        int r = wave * (ROWS / 4) + rr;
        float xxn = xx[b * NN + n0 + r];
        float v[16];
#pragma unroll
        for (int j = 0; j < 16; ++j) v[j] = S[r * NN + lane + 64 * j] - xxn;
        int* gi = gidx + (size_t)b * NN + n0 + r;
        for (int it = 0; it < KK; ++it) {
            float bv = v[0]; int bj = 0;
#pragma unroll
            for (int j = 1; j < 16; ++j) if (v[j] > bv) { bv = v[j]; bj = j; }
            int bm = lane + 64 * bj;
#pragma unroll
            for (int off = 32; off >= 1; off >>= 1) {
                float ov = __shfl_xor(bv, off);
                int   om = __shfl_xor(bm, off);
                if (ov > bv || (ov == bv && om < bm)) { bv = ov; bm = om; }
            }
            if (lane == 0) gi[(size_t)it * BBNN] = bm;
#pragma unroll
            for (int j = 0; j < 16; ++j) if (lane + 64 * j == bm) v[j] = -INFINITY;
        }
    }
}

// ---------------- ya = w_a @ x ; yc = (w_b - w_a) @ x  (weights LDS-staged) ----------------
__global__ __launch_bounds__(256) void yab_kernel(const float* __restrict__ x, int C, int bstride,
                                                  const float* __restrict__ w, int O,
                                                  float* __restrict__ ya, float* __restrict__ yc) {
    extern __shared__ float wls[];       // [8*C] wa, then [8*C] wc
    int tid = threadIdx.x;
    int opb = O >> 3;
    int b  = blockIdx.x / opb;
    int o0 = (blockIdx.x % opb) << 3;
    const float* xb = x + (size_t)b * bstride;

    for (int t = tid; t < 8 * C; t += 256) {
        int r = t / C, c = t - r * C;
        float wa = w[(size_t)(o0 + r) * 2 * C + c];
        float wb = w[(size_t)(o0 + r) * 2 * C + C + c];
        wls[t] = wa;
        wls[8 * C + t] = wb - wa;
    }
    __syncthreads();

    float a[8][4], cv[8][4];
#pragma unroll
    for (int r = 0; r < 8; ++r)
#pragma unroll
        for (int j = 0; j < 4; ++j) { a[r][j] = 0.f; cv[r][j] = 0.f; }
    for (int c = 0; c < C; ++c) {
        float4 xm = *(const float4*)&xb[c * NN + (tid << 2)];
#pragma unroll
        for (int r = 0; r < 8; ++r) {
            float wa = wls[r * C + c];
            float wc = wls[8 * C + r * C + c];
            a[r][0]  = fmaf(wa, xm.x, a[r][0]);  cv[r][0] = fmaf(wc, xm.x, cv[r][0]);
            a[r][1]  = fmaf(wa, xm.y, a[r][1]);  cv[r][1] = fmaf(wc, xm.y, cv[r][1]);
            a[r][2]  = fmaf(wa, xm.z, a[r][2]);  cv[r][2] = fmaf(wc, xm.z, cv[r][2]);
            a[r][3]  = fmaf(wa, xm.w, a[r][3]);  cv[r][3] = fmaf(wc, xm.w, cv[r][3]);
        }
    }
#pragma unroll
    for (int r = 0; r < 8; ++r) {
        size_t off = ((size_t)b * O + o0 + r) * NN + (tid << 2);
        *(float4*)&ya[off] = *(float4*)&a[r][0];
        *(float4*)&yc[off] = *(float4*)&cv[r][0];
    }
}

// ---------------- gmax: out = lrelu(bn(max_k ya[o][idx]+yc[o][n])), 8 o-rows LDS-staged ----------------
__global__ __launch_bounds__(256) void gmax8_kernel(const float* __restrict__ ya, const float* __restrict__ yc,
                                                    const int* __restrict__ gidx, const float* __restrict__ bnp,
                                                    int O, float* __restrict__ outp, int out_bstride) {
    __shared__ float yrow[8 * NN];       // 32 KB
    int tid = threadIdx.x;
    int nt   = blockIdx.x & 3;
    int rest = blockIdx.x >> 2;
    int opb = O >> 3;
    int oc = rest % opb;
    int b  = rest / opb;
    int o0 = oc << 3;
    int n  = (nt << 8) + tid;

    for (int t = tid; t < 8 * NN; t += 256)
        yrow[t] = ya[((size_t)b * O + o0 + (t >> 10)) * NN + (t & 1023)];
    __syncthreads();

    int idx[KK];
    const int* gi = gidx + (size_t)b * NN + n;
#pragma unroll
    for (int k = 0; k < KK; ++k) idx[k] = gi[(size_t)k * BBNN];

#pragma unroll
    for (int r = 0; r < 8; ++r) {
        float m = -INFINITY;
#pragma unroll 8
        for (int k = 0; k < KK; ++k) m = fmaxf(m, yrow[r * NN + idx[k]]);
        m += yc[((size_t)b * O + o0 + r) * NN + n];
        int o = o0 + r;
        float sc = bnp[o] * rsqrtf(bnp[3 * O + o] + EPSF);
        float t0 = (m - bnp[2 * O + o]) * sc + bnp[O + o];
        outp[(size_t)b * out_bstride + (size_t)o * NN + n] = t0 >= 0.f ? t0 : 0.2f * t0;
    }
}

// ---------------- emb v4: XCD-local, LDS w5 tile, 8o x 4n, c-unroll x8 ----------------
__global__ __launch_bounds__(256) void emb_kernel(const float* __restrict__ xc, const float* __restrict__ w5,
                                                  const float* __restrict__ bnp, float* __restrict__ g) {
    __shared__ float wlds[8][512];       // 16 KB
    __shared__ float rmax[8][4], rsum[8][4];
    int tid = threadIdx.x;
    int b  = blockIdx.x & 7;             // XCD-local batches
    int o0 = (blockIdx.x >> 3) << 3;
    const float* xcb = xc + (size_t)b * 512 * NN;

#pragma unroll
    for (int i = 0; i < 4; ++i) {
        int t = tid + (i << 8);
        int row = t >> 7, col = (t & 127) << 2;
        *(float4*)&wlds[row][col] = *(const float4*)&w5[(size_t)(o0 + row) * 512 + col];
    }
    __syncthreads();

    int n4 = tid << 2;
    float acc[8][4];
#pragma unroll
    for (int r = 0; r < 8; ++r)
#pragma unroll
        for (int j = 0; j < 4; ++j) acc[r][j] = 0.f;

    for (int c8 = 0; c8 < 64; ++c8) {
        int c = c8 << 3;
        float4 xm[8];
#pragma unroll
        for (int i = 0; i < 8; ++i)
            xm[i] = *(const float4*)&xcb[(c + i) * NN + n4];
#pragma unroll
        for (int r = 0; r < 8; ++r) {
            float4 wv0 = *(const float4*)&wlds[r][c];
            float4 wv1 = *(const float4*)&wlds[r][c + 4];
            acc[r][0] = fmaf(wv0.x, xm[0].x, acc[r][0]);
            acc[r][1] = fmaf(wv0.x, xm[0].y, acc[r][1]);
            acc[r][2] = fmaf(wv0.x, xm[0].z, acc[r][2]);
            acc[r][3] = fmaf(wv0.x, xm[0].w, acc[r][3]);
            acc[r][0] = fmaf(wv0.y, xm[1].x, acc[r][0]);
            acc[r][1] = fmaf(wv0.y, xm[1].y, acc[r][1]);
            acc[r][2] = fmaf(wv0.y, xm[1].z, acc[r][2]);
            acc[r][3] = fmaf(wv0.y, xm[1].w, acc[r][3]);
            acc[r][0] = fmaf(wv0.z, xm[2].x, acc[r][0]);
            acc[r][1] = fmaf(wv0.z, xm[2].y, acc[r][1]);
            acc[r][2] = fmaf(wv0.z, xm[2].z, acc[r][2]);
            acc[r][3] = fmaf(wv0.z, xm[2].w, acc[r][3]);
            acc[r][0] = fmaf(wv0.w, xm[3].x, acc[r][0]);
            acc[r][1] = fmaf(wv0.w, xm[3].y, acc[r][1]);
            acc[r][2] = fmaf(wv0.w, xm[3].z, acc[r][2]);
            acc[r][3] = fmaf(wv0.w, xm[3].w, acc[r][3]);
            acc[r][0] = fmaf(wv1.x, xm[4].x, acc[r][0]);
            acc[r][1] = fmaf(wv1.x, xm[4].y, acc[r][1]);
            acc[r][2] = fmaf(wv1.x, xm[4].z, acc[r][2]);
            acc[r][3] = fmaf(wv1.x, xm[4].w, acc[r][3]);
            acc[r][0] = fmaf(wv1.y, xm[5].x, acc[r][0]);
            acc[r][1] = fmaf(wv1.y, xm[5].y, acc[r][1]);
            acc[r][2] = fmaf(wv1.y, xm[5].z, acc[r][2]);
            acc[r][3] = fmaf(wv1.y, xm[5].w, acc[r][3]);
            acc[r][0] = fmaf(wv1.z, xm[6].x, acc[r][0]);
            acc[r][1] = fmaf(wv1.z, xm[6].y, acc[r][1]);
            acc[r][2] = fmaf(wv1.z, xm[6].z, acc[r][2]);
            acc[r][3] = fmaf(wv1.z, xm[6].w, acc[r][3]);
            acc[r][0] = fmaf(wv1.w, xm[7].x, acc[r][0]);
            acc[r][1] = fmaf(wv1.w, xm[7].y, acc[r][1]);
            acc[r][2] = fmaf(wv1.w, xm[7].z, acc[r][2]);
            acc[r][3] = fmaf(wv1.w, xm[7].w, acc[r][3]);
        }
    }

    int lane = tid & 63, wave = tid >> 6;
#pragma unroll
    for (int r = 0; r < 8; ++r) {
        int o = o0 + r;
        float sc = bnp[o] * rsqrtf(bnp[3 * EMBD + o] + EPSF);
        float mu = bnp[2 * EMBD + o], be = bnp[EMBD + o];
        float vmax = -INFINITY, vsum = 0.f;
#pragma unroll
        for (int j = 0; j < 4; ++j) {
            float t0 = (acc[r][j] - mu) * sc + be;
            t0 = t0 >= 0.f ? t0 : 0.2f * t0;
            vmax = fmaxf(vmax, t0);
            vsum += t0;
        }
#pragma unroll
        for (int off = 32; off >= 1; off >>= 1) {
            vmax = fmaxf(vmax, __shfl_xor(vmax, off));
            vsum += __shfl_xor(vsum, off);
        }
        if (lane == 0) { rmax[r][wave] = vmax; rsum[r][wave] = vsum; }
    }
    __syncthreads();
    if (tid < 8) {
        float vm = fmaxf(fmaxf(rmax[tid][0], rmax[tid][1]), fmaxf(rmax[tid][2], rmax[tid][3]));
        g[(size_t)b * 2 * EMBD + o0 + tid] = vm;
    } else if (tid < 16) {
        int r = tid - 8;
        float vs = rsum[r][0] + rsum[r][1] + rsum[r][2] + rsum[r][3];
        g[(size_t)b * 2 * EMBD + EMBD + o0 + r] = vs * (1.0f / 1024.0f);
    }
}

// ---------------- naive head1: one block per (b,o) ----------------
__global__ __launch_bounds__(256) void head1_naive_kernel(const float* __restrict__ g, const float* __restrict__ l1,
                                                          const float* __restrict__ bnp, float* __restrict__ h1) {
    __shared__ float red[256];
    int tid = threadIdx.x;
    int b = blockIdx.x >> 9, o = blockIdx.x & 511;
    const float* gr = g + (size_t)b * 2 * EMBD;
    const float* lr = l1 + (size_t)o * 2 * EMBD;
    float s = 0.f;
    for (int c = tid; c < 2048; c += 256) s = fmaf(gr[c], lr[c], s);
    red[tid] = s;
    __syncthreads();
    for (int st = 128; st >= 1; st >>= 1) {
        if (tid < st) red[tid] += red[tid + st];
        __syncthreads();
    }
    if (tid == 0) {
        float sc = bnp[o] * rsqrtf(bnp[3 * 512 + o] + EPSF);
        float t0 = (red[0] - bnp[2 * 512 + o]) * sc + bnp[512 + o];
        h1[b * 512 + o] = t0 >= 0.f ? t0 : 0.2f * t0;
    }
}

// ---------------- naive head2: one block per (b,o) ----------------
__global__ __launch_bounds__(256) void head2_naive_kernel(const float* __restrict__ h1, const float* __restrict__ l2w,
                                                          const float* __restrict__ l2b, const float* __restrict__ bnp,
                                                          float* __restrict__ h2) {
    __shared__ float red[256];
    int tid = threadIdx.x;
    int b = blockIdx.x >> 8, o = blockIdx.x & 255;
    const float* hr = h1 + (size_t)b * 512;
    const float* lr = l2w + (size_t)o * 512;
    float s = fmaf(hr[tid], lr[tid], hr[tid + 256] * lr[tid + 256]);
    red[tid] = s;
    __syncthreads();
    for (int st = 128; st >= 1; st >>= 1) {
        if (tid < st) red[tid] += red[tid + st];
        __syncthreads();
    }
    if (tid == 0) {
        float v = red[0] + l2b[o];
        float sc = bnp[o] * rsqrtf(bnp[3 * 256 + o] + EPSF);
        float t0 = (v - bnp[2 * 256 + o]) * sc + bnp[256 + o];
        h2[b * 256 + o] = t0 >= 0.f ? t0 : 0.2f * t0;
    }
}

// ---------------- naive head3: one block per (b,i) -> logits scratch ----------------
__global__ __launch_bounds__(256) void head3_naive_kernel(const float* __restrict__ h2, const float* __restrict__ l3w,
                                                          const float* __restrict__ l3b, float* __restrict__ logits) {
    __shared__ float red[256];
    int tid = threadIdx.x;
    int b = blockIdx.x / 40, i = blockIdx.x % 40;
    red[tid] = h2[(size_t)b * 256 + tid] * l3w[(size_t)i * 256 + tid];
    __syncthreads();
    for (int st = 128; st >= 1; st >>= 1) {
        if (tid < st) red[tid] += red[tid + st];
        __syncthreads();
    }
    if (tid == 0) logits[b * 40 + i] = red[0] + l3b[i];
}

// ---------------- final: out[0..319]=logits (f32), out[320..639]=log_softmax (f32) ----------------
__global__ void final_kernel(const float* __restrict__ logits, float* __restrict__ outp) {
    int b = blockIdx.x;
    if (threadIdx.x != 0) return;
    const float* lr = logits + b * 40;
    float mx = lr[0];
    for (int i = 1; i < 40; ++i) mx = fmaxf(mx, lr[i]);
    float se = 0.f;
    for (int i = 0; i < 40; ++i) se += expf(lr[i] - mx);
    float lse = logf(se);
    for (int i = 0; i < 40; ++i) {
        outp[b * 40 + i]            = lr[i];
        outp[BB * 40 + b * 40 + i]  = lr[i] - mx - lse;
    }
}

extern "C" void kernel_launch(void* const* d_in, const int* in_sizes, int n_in,
                              void* d_out, int out_size, void* d_ws, size_t ws_size,
                              hipStream_t stream) {
    const float* x   = (const float*)d_in[0];
    const float* w1  = (const float*)d_in[1];
    const float* w2  = (const float*)d_in[2];
    const float* w3  = (const float*)d_in[3];
    const float* w4  = (const float*)d_in[4];
    const float* w5  = (const float*)d_in[5];
    const float* l1  = (const float*)d_in[6];
    const float* l2w = (const float*)d_in[7];
    const float* l2b = (const float*)d_in[8];
    const float* l3w = (const float*)d_in[9];
    const float* l3b = (const float*)d_in[10];
    const float* bn1 = (const float*)d_in[11];
    const float* bn2 = (const float*)d_in[12];
    const float* bn3 = (const float*)d_in[13];
    const float* bn4 = (const float*)d_in[14];
    const float* bn5 = (const float*)d_in[15];
    const float* bn6 = (const float*)d_in[16];
    const float* bn7 = (const float*)d_in[17];
    float* outp = (float*)d_out;   // reference outputs are float32

    // workspace carve (floats): xc | ya | yc | xx | gidx | g | h1 | h2 | logits
    float* xc     = (float*)d_ws;
    float* ya     = xc  + (size_t)BB * 512 * NN;
    float* ycb    = ya  + (size_t)BB * 256 * NN;
    float* xxb    = ycb + (size_t)BB * 256 * NN;
    int*  gidx    = (int*)(xxb + BB * NN);
    float* g      = (float*)(gidx + (size_t)BB * NN * KK);
    float* h1     = g  + BB * 2 * EMBD;
    float* h2     = h1 + BB * 512;
    float* logits = h2 + BB * 256;

    struct Layer { const float* xin; int C; int bstride; const float* w; const float* bn; int O; float* out; };
    Layer L[4] = {
        { x,            3,   3 * NN,   w1, bn1, 64,  xc            },
        { xc,           64,  512 * NN, w2, bn2, 64,  xc + 64 * NN  },
        { xc + 64 * NN, 64,  512 * NN, w3, bn3, 128, xc + 128 * NN },
        { xc + 128 * NN,128, 512 * NN, w4, bn4, 256, xc + 256 * NN },
    };

    for (int i = 0; i < 4; ++i) {
        xx_kernel<<<dim3(BB * NN / 256), dim3(256), 0, stream>>>(L[i].xin, L[i].C, L[i].bstride, xxb);
        knn_kernel<<<dim3(BB * (NN / ROWS)), dim3(256), 0, stream>>>(L[i].xin, L[i].C, L[i].bstride, xxb, gidx);
        size_t wlds = (size_t)2 * 8 * L[i].C * sizeof(float);
        yab_kernel<<<dim3(BB * L[i].O / 8), dim3(256), wlds, stream>>>(L[i].xin, L[i].C, L[i].bstride, L[i].w, L[i].O, ya, ycb);
        gmax8_kernel<<<dim3(BB * (L[i].O / 8) * 4), dim3(256), 0, stream>>>(ya, ycb, gidx, L[i].bn, L[i].O, L[i].out, 512 * NN);
    }
    emb_kernel<<<dim3(BB * 128), dim3(256), 0, stream>>>(xc, w5, bn5, g);
    head1_naive_kernel<<<dim3(BB * 512), dim3(256), 0, stream>>>(g, l1, bn6, h1);
    head2_naive_kernel<<<dim3(BB * 256), dim3(256), 0, stream>>>(h1, l2w, l2b, bn7, h2);
    head3_naive_kernel<<<dim3(BB * 40), dim3(256), 0, stream>>>(h2, l3w, l3b, logits);
    final_kernel<<<dim3(BB), dim3(64), 0, stream>>>(logits, outp);
}

// Round 11
// 785.958 us; speedup vs baseline: 1.2901x; 1.1516x over previous
//
#include <hip/hip_runtime.h>
#include <hip/hip_bf16.h>
#include <math.h>

#define BB 8
#define NN 1024
#define KK 40
#define EMBD 1024
#define EPSF 1e-5f
#define ROWS 8
#define BBNN (BB * NN)

// ---------------- fused layer front: knn (blocks 0..BB*128) + yab (rest) ----------------
// knn: 8 query rows/block; inline xx; score s[m] = 2*dot(x_n,x_m) - xx[m]  (row-const -xx[n] dropped)
// yab: ya = w_a @ x ; yc = (w_b - w_a) @ x, weights LDS-staged
// gidx written TRANSPOSED: gidx[k*BBNN + b*NN + n]
__global__ __launch_bounds__(256) void layer_kernel(const float* __restrict__ x, int C, int bstride,
                                                    const float* __restrict__ w, int O,
                                                    int* __restrict__ gidx,
                                                    float* __restrict__ ya, float* __restrict__ yc) {
    extern __shared__ float lds[];
    int tid = threadIdx.x;

    if (blockIdx.x < BB * 128) {
        // ================= knn role =================
        float* S    = lds;               // ROWS*NN = 32 KB
        float* CENT = lds + ROWS * NN;   // 64*ROWS = 2 KB
        int b = blockIdx.x >> 7;
        int n0 = (blockIdx.x & 127) * ROWS;
        const float* xb = x + (size_t)b * bstride;

        float acc[ROWS][4];
        float xxa[4] = {0.f, 0.f, 0.f, 0.f};
#pragma unroll
        for (int r = 0; r < ROWS; ++r)
#pragma unroll
            for (int j = 0; j < 4; ++j) acc[r][j] = 0.f;

        for (int c0 = 0; c0 < C; c0 += 64) {
            int cc = C - c0; if (cc > 64) cc = 64;
            for (int t = tid; t < cc * ROWS; t += 256)
                CENT[t] = xb[(c0 + t / ROWS) * NN + n0 + (t & (ROWS - 1))];
            __syncthreads();
            for (int ci = 0; ci < cc; ++ci) {
                float4 xm = *(const float4*)&xb[(c0 + ci) * NN + (tid << 2)];
                xxa[0] = fmaf(xm.x, xm.x, xxa[0]);
                xxa[1] = fmaf(xm.y, xm.y, xxa[1]);
                xxa[2] = fmaf(xm.z, xm.z, xxa[2]);
                xxa[3] = fmaf(xm.w, xm.w, xxa[3]);
#pragma unroll
                for (int r = 0; r < ROWS; ++r) {
                    float ce = CENT[ci * ROWS + r];
                    acc[r][0] = fmaf(ce, xm.x, acc[r][0]);
                    acc[r][1] = fmaf(ce, xm.y, acc[r][1]);
                    acc[r][2] = fmaf(ce, xm.z, acc[r][2]);
                    acc[r][3] = fmaf(ce, xm.w, acc[r][3]);
                }
            }
            __syncthreads();
        }
#pragma unroll
        for (int r = 0; r < ROWS; ++r) {
            float4 sv;
            sv.x = 2.f * acc[r][0] - xxa[0];
            sv.y = 2.f * acc[r][1] - xxa[1];
            sv.z = 2.f * acc[r][2] - xxa[2];
            sv.w = 2.f * acc[r][3] - xxa[3];
            *(float4*)&S[r * NN + (tid << 2)] = sv;
        }
        __syncthreads();

        // selection: each wave owns 2 rows; 64 lanes x 16 values in registers
        int wave = tid >> 6, lane = tid & 63;
        for (int rr = 0; rr < ROWS / 4; ++rr) {
            int r = wave * (ROWS / 4) + rr;
            float v[16];
#pragma unroll
            for (int j = 0; j < 16; ++j) v[j] = S[r * NN + lane + 64 * j];
            int* gi = gidx + (size_t)b * NN + n0 + r;
            for (int it = 0; it < KK; ++it) {
                float bv = v[0]; int bj = 0;
#pragma unroll
                for (int j = 1; j < 16; ++j) if (v[j] > bv) { bv = v[j]; bj = j; }
                int bm = lane + 64 * bj;
#pragma unroll
                for (int off = 32; off >= 1; off >>= 1) {
                    float ov = __shfl_xor(bv, off);
                    int   om = __shfl_xor(bm, off);
                    if (ov > bv || (ov == bv && om < bm)) { bv = ov; bm = om; }
                }
                if (lane == 0) gi[(size_t)it * BBNN] = bm;
#pragma unroll
                for (int j = 0; j < 16; ++j) if (lane + 64 * j == bm) v[j] = -INFINITY;
            }
        }
    } else {
        // ================= yab role =================
        int bid = blockIdx.x - BB * 128;
        float* wls = lds;                // [8*C] wa, then [8*C] wc
        int opb = O >> 3;
        int b  = bid / opb;
        int o0 = (bid % opb) << 3;
        const float* xb = x + (size_t)b * bstride;

        for (int t = tid; t < 8 * C; t += 256) {
            int r = t / C, c = t - r * C;
            float wa = w[(size_t)(o0 + r) * 2 * C + c];
            float wb = w[(size_t)(o0 + r) * 2 * C + C + c];
            wls[t] = wa;
            wls[8 * C + t] = wb - wa;
        }
        __syncthreads();

        float a[8][4], cv[8][4];
#pragma unroll
        for (int r = 0; r < 8; ++r)
#pragma unroll
            for (int j = 0; j < 4; ++j) { a[r][j] = 0.f; cv[r][j] = 0.f; }
        for (int c = 0; c < C; ++c) {
            float4 xm = *(const float4*)&xb[c * NN + (tid << 2)];
#pragma unroll
            for (int r = 0; r < 8; ++r) {
                float wa = wls[r * C + c];
                float wc = wls[8 * C + r * C + c];
                a[r][0]  = fmaf(wa, xm.x, a[r][0]);  cv[r][0] = fmaf(wc, xm.x, cv[r][0]);
                a[r][1]  = fmaf(wa, xm.y, a[r][1]);  cv[r][1] = fmaf(wc, xm.y, cv[r][1]);
                a[r][2]  = fmaf(wa, xm.z, a[r][2]);  cv[r][2] = fmaf(wc, xm.z, cv[r][2]);
                a[r][3]  = fmaf(wa, xm.w, a[r][3]);  cv[r][3] = fmaf(wc, xm.w, cv[r][3]);
            }
        }
#pragma unroll
        for (int r = 0; r < 8; ++r) {
            size_t off = ((size_t)b * O + o0 + r) * NN + (tid << 2);
            *(float4*)&ya[off] = *(float4*)&a[r][0];
            *(float4*)&yc[off] = *(float4*)&cv[r][0];
        }
    }
}

// ---------------- gmax: out = lrelu(bn(max_k ya[o][idx]+yc[o][n])), 8 o-rows LDS-staged ----------------
__global__ __launch_bounds__(256) void gmax8_kernel(const float* __restrict__ ya, const float* __restrict__ yc,
                                                    const int* __restrict__ gidx, const float* __restrict__ bnp,
                                                    int O, float* __restrict__ outp, int out_bstride) {
    __shared__ float yrow[8 * NN];       // 32 KB
    int tid = threadIdx.x;
    int nt   = blockIdx.x & 3;
    int rest = blockIdx.x >> 2;
    int opb = O >> 3;
    int oc = rest % opb;
    int b  = rest / opb;
    int o0 = oc << 3;
    int n  = (nt << 8) + tid;

    for (int t = tid; t < 8 * NN; t += 256)
        yrow[t] = ya[((size_t)b * O + o0 + (t >> 10)) * NN + (t & 1023)];
    __syncthreads();

    int idx[KK];
    const int* gi = gidx + (size_t)b * NN + n;
#pragma unroll
    for (int k = 0; k < KK; ++k) idx[k] = gi[(size_t)k * BBNN];

#pragma unroll
    for (int r = 0; r < 8; ++r) {
        float m = -INFINITY;
#pragma unroll 8
        for (int k = 0; k < KK; ++k) m = fmaxf(m, yrow[r * NN + idx[k]]);
        m += yc[((size_t)b * O + o0 + r) * NN + n];
        int o = o0 + r;
        float sc = bnp[o] * rsqrtf(bnp[3 * O + o] + EPSF);
        float t0 = (m - bnp[2 * O + o]) * sc + bnp[O + o];
        outp[(size_t)b * out_bstride + (size_t)o * NN + n] = t0 >= 0.f ? t0 : 0.2f * t0;
    }
}

// ---------------- emb: XCD-local, LDS w5 tile, 8o x 4n, c-unroll x8 (x2 pipelined) ----------------
__global__ __launch_bounds__(256) void emb_kernel(const float* __restrict__ xc, const float* __restrict__ w5,
                                                  const float* __restrict__ bnp, float* __restrict__ g) {
    __shared__ float wlds[8][512];       // 16 KB
    __shared__ float rmax[8][4], rsum[8][4];
    int tid = threadIdx.x;
    int b  = blockIdx.x & 7;             // XCD-local batches
    int o0 = (blockIdx.x >> 3) << 3;
    const float* xcb = xc + (size_t)b * 512 * NN;

#pragma unroll
    for (int i = 0; i < 4; ++i) {
        int t = tid + (i << 8);
        int row = t >> 7, col = (t & 127) << 2;
        *(float4*)&wlds[row][col] = *(const float4*)&w5[(size_t)(o0 + row) * 512 + col];
    }
    __syncthreads();

    int n4 = tid << 2;
    float acc[8][4];
#pragma unroll
    for (int r = 0; r < 8; ++r)
#pragma unroll
        for (int j = 0; j < 4; ++j) acc[r][j] = 0.f;

#pragma unroll 2
    for (int c8 = 0; c8 < 64; ++c8) {
        int c = c8 << 3;
        float4 xm[8];
#pragma unroll
        for (int i = 0; i < 8; ++i)
            xm[i] = *(const float4*)&xcb[(c + i) * NN + n4];
#pragma unroll
        for (int r = 0; r < 8; ++r) {
            float4 wv0 = *(const float4*)&wlds[r][c];
            float4 wv1 = *(const float4*)&wlds[r][c + 4];
            acc[r][0] = fmaf(wv0.x, xm[0].x, acc[r][0]);
            acc[r][1] = fmaf(wv0.x, xm[0].y, acc[r][1]);
            acc[r][2] = fmaf(wv0.x, xm[0].z, acc[r][2]);
            acc[r][3] = fmaf(wv0.x, xm[0].w, acc[r][3]);
            acc[r][0] = fmaf(wv0.y, xm[1].x, acc[r][0]);
            acc[r][1] = fmaf(wv0.y, xm[1].y, acc[r][1]);
            acc[r][2] = fmaf(wv0.y, xm[1].z, acc[r][2]);
            acc[r][3] = fmaf(wv0.y, xm[1].w, acc[r][3]);
            acc[r][0] = fmaf(wv0.z, xm[2].x, acc[r][0]);
            acc[r][1] = fmaf(wv0.z, xm[2].y, acc[r][1]);
            acc[r][2] = fmaf(wv0.z, xm[2].z, acc[r][2]);
            acc[r][3] = fmaf(wv0.z, xm[2].w, acc[r][3]);
            acc[r][0] = fmaf(wv0.w, xm[3].x, acc[r][0]);
            acc[r][1] = fmaf(wv0.w, xm[3].y, acc[r][1]);
            acc[r][2] = fmaf(wv0.w, xm[3].z, acc[r][2]);
            acc[r][3] = fmaf(wv0.w, xm[3].w, acc[r][3]);
            acc[r][0] = fmaf(wv1.x, xm[4].x, acc[r][0]);
            acc[r][1] = fmaf(wv1.x, xm[4].y, acc[r][1]);
            acc[r][2] = fmaf(wv1.x, xm[4].z, acc[r][2]);
            acc[r][3] = fmaf(wv1.x, xm[4].w, acc[r][3]);
            acc[r][0] = fmaf(wv1.y, xm[5].x, acc[r][0]);
            acc[r][1] = fmaf(wv1.y, xm[5].y, acc[r][1]);
            acc[r][2] = fmaf(wv1.y, xm[5].z, acc[r][2]);
            acc[r][3] = fmaf(wv1.y, xm[5].w, acc[r][3]);
            acc[r][0] = fmaf(wv1.z, xm[6].x, acc[r][0]);
            acc[r][1] = fmaf(wv1.z, xm[6].y, acc[r][1]);
            acc[r][2] = fmaf(wv1.z, xm[6].z, acc[r][2]);
            acc[r][3] = fmaf(wv1.z, xm[6].w, acc[r][3]);
            acc[r][0] = fmaf(wv1.w, xm[7].x, acc[r][0]);
            acc[r][1] = fmaf(wv1.w, xm[7].y, acc[r][1]);
            acc[r][2] = fmaf(wv1.w, xm[7].z, acc[r][2]);
            acc[r][3] = fmaf(wv1.w, xm[7].w, acc[r][3]);
        }
    }

    int lane = tid & 63, wave = tid >> 6;
#pragma unroll
    for (int r = 0; r < 8; ++r) {
        int o = o0 + r;
        float sc = bnp[o] * rsqrtf(bnp[3 * EMBD + o] + EPSF);
        float mu = bnp[2 * EMBD + o], be = bnp[EMBD + o];
        float vmax = -INFINITY, vsum = 0.f;
#pragma unroll
        for (int j = 0; j < 4; ++j) {
            float t0 = (acc[r][j] - mu) * sc + be;
            t0 = t0 >= 0.f ? t0 : 0.2f * t0;
            vmax = fmaxf(vmax, t0);
            vsum += t0;
        }
#pragma unroll
        for (int off = 32; off >= 1; off >>= 1) {
            vmax = fmaxf(vmax, __shfl_xor(vmax, off));
            vsum += __shfl_xor(vsum, off);
        }
        if (lane == 0) { rmax[r][wave] = vmax; rsum[r][wave] = vsum; }
    }
    __syncthreads();
    if (tid < 8) {
        float vm = fmaxf(fmaxf(rmax[tid][0], rmax[tid][1]), fmaxf(rmax[tid][2], rmax[tid][3]));
        g[(size_t)b * 2 * EMBD + o0 + tid] = vm;
    } else if (tid < 16) {
        int r = tid - 8;
        float vs = rsum[r][0] + rsum[r][1] + rsum[r][2] + rsum[r][3];
        g[(size_t)b * 2 * EMBD + EMBD + o0 + r] = vs * (1.0f / 1024.0f);
    }
}

// ---------------- naive head1: one block per (b,o) ----------------
__global__ __launch_bounds__(256) void head1_naive_kernel(const float* __restrict__ g, const float* __restrict__ l1,
                                                          const float* __restrict__ bnp, float* __restrict__ h1) {
    __shared__ float red[256];
    int tid = threadIdx.x;
    int b = blockIdx.x >> 9, o = blockIdx.x & 511;
    const float* gr = g + (size_t)b * 2 * EMBD;
    const float* lr = l1 + (size_t)o * 2 * EMBD;
    float s = 0.f;
    for (int c = tid; c < 2048; c += 256) s = fmaf(gr[c], lr[c], s);
    red[tid] = s;
    __syncthreads();
    for (int st = 128; st >= 1; st >>= 1) {
        if (tid < st) red[tid] += red[tid + st];
        __syncthreads();
    }
    if (tid == 0) {
        float sc = bnp[o] * rsqrtf(bnp[3 * 512 + o] + EPSF);
        float t0 = (red[0] - bnp[2 * 512 + o]) * sc + bnp[512 + o];
        h1[b * 512 + o] = t0 >= 0.f ? t0 : 0.2f * t0;
    }
}

// ---------------- naive head2: one block per (b,o) ----------------
__global__ __launch_bounds__(256) void head2_naive_kernel(const float* __restrict__ h1, const float* __restrict__ l2w,
                                                          const float* __restrict__ l2b, const float* __restrict__ bnp,
                                                          float* __restrict__ h2) {
    __shared__ float red[256];
    int tid = threadIdx.x;
    int b = blockIdx.x >> 8, o = blockIdx.x & 255;
    const float* hr = h1 + (size_t)b * 512;
    const float* lr = l2w + (size_t)o * 512;
    float s = fmaf(hr[tid], lr[tid], hr[tid + 256] * lr[tid + 256]);
    red[tid] = s;
    __syncthreads();
    for (int st = 128; st >= 1; st >>= 1) {
        if (tid < st) red[tid] += red[tid + st];
        __syncthreads();
    }
    if (tid == 0) {
        float v = red[0] + l2b[o];
        float sc = bnp[o] * rsqrtf(bnp[3 * 256 + o] + EPSF);
        float t0 = (v - bnp[2 * 256 + o]) * sc + bnp[256 + o];
        h2[b * 256 + o] = t0 >= 0.f ? t0 : 0.2f * t0;
    }
}

// ---------------- naive head3: one block per (b,i) -> logits scratch ----------------
__global__ __launch_bounds__(256) void head3_naive_kernel(const float* __restrict__ h2, const float* __restrict__ l3w,
                                                          const float* __restrict__ l3b, float* __restrict__ logits) {
    __shared__ float red[256];
    int tid = threadIdx.x;
    int b = blockIdx.x / 40, i = blockIdx.x % 40;
    red[tid] = h2[(size_t)b * 256 + tid] * l3w[(size_t)i * 256 + tid];
    __syncthreads();
    for (int st = 128; st >= 1; st >>= 1) {
        if (tid < st) red[tid] += red[tid + st];
        __syncthreads();
    }
    if (tid == 0) logits[b * 40 + i] = red[0] + l3b[i];
}

// ---------------- final: out[0..319]=logits (f32), out[320..639]=log_softmax (f32) ----------------
__global__ void final_kernel(const float* __restrict__ logits, float* __restrict__ outp) {
    int b = blockIdx.x;
    if (threadIdx.x != 0) return;
    const float* lr = logits + b * 40;
    float mx = lr[0];
    for (int i = 1; i < 40; ++i) mx = fmaxf(mx, lr[i]);
    float se = 0.f;
    for (int i = 0; i < 40; ++i) se += expf(lr[i] - mx);
    float lse = logf(se);
    for (int i = 0; i < 40; ++i) {
        outp[b * 40 + i]            = lr[i];
        outp[BB * 40 + b * 40 + i]  = lr[i] - mx - lse;
    }
}

extern "C" void kernel_launch(void* const* d_in, const int* in_sizes, int n_in,
                              void* d_out, int out_size, void* d_ws, size_t ws_size,
                              hipStream_t stream) {
    const float* x   = (const float*)d_in[0];
    const float* w1  = (const float*)d_in[1];
    const float* w2  = (const float*)d_in[2];
    const float* w3  = (const float*)d_in[3];
    const float* w4  = (const float*)d_in[4];
    const float* w5  = (const float*)d_in[5];
    const float* l1  = (const float*)d_in[6];
    const float* l2w = (const float*)d_in[7];
    const float* l2b = (const float*)d_in[8];
    const float* l3w = (const float*)d_in[9];
    const float* l3b = (const float*)d_in[10];
    const float* bn1 = (const float*)d_in[11];
    const float* bn2 = (const float*)d_in[12];
    const float* bn3 = (const float*)d_in[13];
    const float* bn4 = (const float*)d_in[14];
    const float* bn5 = (const float*)d_in[15];
    const float* bn6 = (const float*)d_in[16];
    const float* bn7 = (const float*)d_in[17];
    float* outp = (float*)d_out;   // reference outputs are float32

    // workspace carve (floats): xc | ya | yc | gidx | g | h1 | h2 | logits
    float* xc     = (float*)d_ws;
    float* ya     = xc  + (size_t)BB * 512 * NN;
    float* ycb    = ya  + (size_t)BB * 256 * NN;
    int*  gidx    = (int*)(ycb + (size_t)BB * 256 * NN);
    float* g      = (float*)(gidx + (size_t)BB * NN * KK);
    float* h1     = g  + BB * 2 * EMBD;
    float* h2     = h1 + BB * 512;
    float* logits = h2 + BB * 256;

    struct Layer { const float* xin; int C; int bstride; const float* w; const float* bn; int O; float* out; };
    Layer L[4] = {
        { x,            3,   3 * NN,   w1, bn1, 64,  xc            },
        { xc,           64,  512 * NN, w2, bn2, 64,  xc + 64 * NN  },
        { xc + 64 * NN, 64,  512 * NN, w3, bn3, 128, xc + 128 * NN },
        { xc + 128 * NN,128, 512 * NN, w4, bn4, 256, xc + 256 * NN },
    };

    size_t lsz = (size_t)(ROWS * NN + 64 * ROWS) * sizeof(float);   // 34.8 KB (knn role dominates)
    for (int i = 0; i < 4; ++i) {
        layer_kernel<<<dim3(BB * 128 + BB * (L[i].O / 8)), dim3(256), lsz, stream>>>(
            L[i].xin, L[i].C, L[i].bstride, L[i].w, L[i].O, gidx, ya, ycb);
        gmax8_kernel<<<dim3(BB * (L[i].O / 8) * 4), dim3(256), 0, stream>>>(ya, ycb, gidx, L[i].bn, L[i].O, L[i].out, 512 * NN);
    }
    emb_kernel<<<dim3(BB * 128), dim3(256), 0, stream>>>(xc, w5, bn5, g);
    head1_naive_kernel<<<dim3(BB * 512), dim3(256), 0, stream>>>(g, l1, bn6, h1);
    head2_naive_kernel<<<dim3(BB * 256), dim3(256), 0, stream>>>(h1, l2w, l2b, bn7, h2);
    head3_naive_kernel<<<dim3(BB * 40), dim3(256), 0, stream>>>(h2, l3w, l3b, logits);
    final_kernel<<<dim3(BB), dim3(64), 0, stream>>>(logits, outp);
}